// Round 1
// baseline (581.351 us; speedup 1.0000x reference)
//
#include <hip/hip_runtime.h>
#include <stdint.h>

// ---------------------------------------------------------------------------
// Binary (sign) weight 3-layer MLP, round 7:
//   convert_x: x f32 [65536,784] -> Xp bf16 [65536,832]
//   gemm1: h1 = relu(Xp @ sign(W1)^T + b1) -> bf16 [65536,1024]
//   gemm2: h2 = relu(h1 @ sign(W2)^T + b2) -> bf16 [65536,512]
//   gemm3: out = h2 @ sign(W3)^T + b3      -> f32  [65536,10]
// R7 core change: gemm1/gemm2 rewritten as 256x256-tile, 8-wave, BK=64,
// double-buffered (128 KiB LDS) kernel with the T2+T3+T4+T5 stack:
//   - 4 phases per K-tile; all LDS reads for tile kt land in P0/P1, then a
//     lgkmcnt(0)-gated raw s_barrier proves buf[cur] is free; P2/P3 issue
//     the 8 global_load_lds for tile kt+2 into buf[cur] under the ks1 MFMAs.
//   - steady-state wait is s_waitcnt vmcnt(8) once per K-tile (never 0).
//   - T2 XOR swizzle slot^=row&7 (write side via pre-swizzled GLOBAL source,
//     read side on ds_read addr) kills the stride-128B bank conflict.
//   - T5 setprio(1) around each 16-MFMA cluster.
//   - T1 bijective XCD swizzle (m-panel-contiguous per XCD) + K-phase
//     rotation by n-index (R4/R6 evidence: lockstep same-line streams
//     collapse HBM).
// ---------------------------------------------------------------------------

typedef __attribute__((ext_vector_type(8))) short bf16x8;
typedef __attribute__((ext_vector_type(4))) float f32x4;

typedef const __attribute__((address_space(1))) unsigned int* as1_u32p;
typedef __attribute__((address_space(3))) unsigned int* as3_u32p;

__device__ __forceinline__ void glds16(const void* g, void* l) {
  __builtin_amdgcn_global_load_lds((as1_u32p)g, (as3_u32p)l, 16, 0, 0);
}

__device__ __forceinline__ unsigned short f2bf(float f) {
  union { float f; unsigned u; } c;
  c.f = f;
  unsigned u = c.u;
  u += 0x7FFFu + ((u >> 16) & 1u);  // RTNE
  return (unsigned short)(u >> 16);
}

// ---------------------------------------------------------------------------
__global__ void binarize_kernel(const float* __restrict__ src, int Ns, int Ks,
                                short* __restrict__ dst, int Np, int Kp) {
  int idx = blockIdx.x * 256 + threadIdx.x;
  if (idx >= Np * Kp) return;
  int n = idx / Kp;
  int k = idx - n * Kp;
  short v = 0;
  if (n < Ns && k < Ks)
    v = (src[n * Ks + k] >= 0.0f) ? (short)0x3F80 : (short)0xBF80;
  dst[idx] = v;
}

// ---------------------------------------------------------------------------
// convert_x: X f32 [65536,784] -> Xp bf16 [65536,832], cols 784..832 zeroed.
// ---------------------------------------------------------------------------
__global__ void convert_x_kernel(const float* __restrict__ X, short* __restrict__ Xp) {
  const int g = blockIdx.x * 256 + threadIdx.x;
  if (g >= 65536 * 104) return;
  const int row = g / 104;
  const int c = (g - row * 104) * 8;
  short tmp[8];
  if (c < 784) {
    const float* s = X + (size_t)row * 784 + c;
    float4 f0 = *(const float4*)s;
    float4 f1 = *(const float4*)(s + 4);
    tmp[0] = (short)f2bf(f0.x); tmp[1] = (short)f2bf(f0.y);
    tmp[2] = (short)f2bf(f0.z); tmp[3] = (short)f2bf(f0.w);
    tmp[4] = (short)f2bf(f1.x); tmp[5] = (short)f2bf(f1.y);
    tmp[6] = (short)f2bf(f1.z); tmp[7] = (short)f2bf(f1.w);
  } else {
#pragma unroll
    for (int i = 0; i < 8; ++i) tmp[i] = 0;
  }
  *(bf16x8*)(Xp + (size_t)row * 832 + c) = *(bf16x8*)(tmp);
}

// ---------------------------------------------------------------------------
// 256x256-tile GEMM, BK=64, 8 waves (2M x 4N), per-wave output 128x64.
// A bf16 [65536,KP] x Wb bf16 [NP,KP] -> relu(.+bias) bf16 [65536,NP]
// LDS: 2 x (A[256][64] + B[256][64]) = 128 KiB, XOR-swizzled slot^=row&7.
// Pipeline: tile kt read from buf[kt&1]; tile kt+2 staged into buf[kt&1]
// during P2/P3 (after the P1 read-complete gate). vmcnt(8) steady state.
// ---------------------------------------------------------------------------
template <int KP, int NKT, int NP, int NR, int NT>
__global__ __launch_bounds__(512, 2)
void gemm256(const short* __restrict__ A, const short* __restrict__ Wb,
             const float* __restrict__ bias, short* __restrict__ Hout) {
  __shared__ short Asm[2][256 * 64];
  __shared__ short Bsm[2][256 * 64];

  // T1: bijective XCD swizzle; consecutive lid (same XCD) share an A-panel.
  constexpr int NWG8 = (256 * NT) >> 3;  // grid = 256 m-tiles * NT n-tiles
  const int d = blockIdx.x;
  const int lid = (d & 7) * NWG8 + (d >> 3);
  const int mi = lid / NT;
  const int ni = lid - mi * NT;
  const int m0 = mi << 8;
  const int n0 = ni << 8;
  const int start = (ni * NKT) / NT;  // K-phase rotation by n-index

  const int tid = threadIdx.x;
  const int lane = tid & 63;
  const int w = tid >> 6;   // wave 0..7
  const int wm = w >> 2;    // 0..1
  const int wn = w & 3;     // 0..3
  const int l15 = lane & 15;
  const int quad = lane >> 4;

  // Staging: per glds round, 512 thr x 16B = 64 rows. Wave w covers rows
  // [rnd*64 + w*8, +8). LDS dest is linear (wave-uniform base + lane*16);
  // the swizzle is applied by permuting the GLOBAL source column:
  //   LDS[row][s] holds global[row][s ^ (row&7)],  s = lane&7, row&7 = lane>>3.
  const int srow = (w << 3) + (lane >> 3);
  const int scol = ((lane & 7) ^ (lane >> 3)) << 3;
  const short* ag = A + (size_t)(m0 + srow) * KP + scol;
  const short* bg = Wb + (size_t)(n0 + srow) * KP + scol;
  short* const la = &Asm[0][0] + (w << 9);  // + pb*16384 + rnd*4096 (shorts)
  short* const lb = &Bsm[0][0] + (w << 9);

  auto stageA = [&](int pb, int kit) {
    const short* s = ag + kit * 64;
    short* dst = la + (pb << 14);
    glds16(s, dst);
    glds16(s + (size_t)64 * KP, dst + 4096);
    glds16(s + (size_t)128 * KP, dst + 8192);
    glds16(s + (size_t)192 * KP, dst + 12288);
  };
  auto stageB = [&](int pb, int kit) {
    const short* s = bg + kit * 64;
    short* dst = lb + (pb << 14);
    glds16(s, dst);
    glds16(s + (size_t)64 * KP, dst + 4096);
    glds16(s + (size_t)128 * KP, dst + 8192);
    glds16(s + (size_t)192 * KP, dst + 12288);
  };

  // Fragment read offsets (shorts). Swizzled slot = pre_slot ^ (row&7),
  // row&7 == l15&7 == lane&7 here (row bases are multiples of 16).
  const int arow = ((wm << 7) + l15) << 6;
  const int brow = ((wn << 6) + l15) << 6;
  const int sl0 = (quad ^ (lane & 7)) << 3;  // ks=0
  const int sl1 = sl0 ^ 32;                  // ks=1 (slot ^ 4)

  f32x4 acc[8][4];
#pragma unroll
  for (int i = 0; i < 8; ++i)
#pragma unroll
    for (int j = 0; j < 4; ++j) acc[i][j] = (f32x4){0.f, 0.f, 0.f, 0.f};

  // Prologue: stage tiles start, start+1; confirm tile0 (oldest 8 of 16).
  int k1 = start + 1; if (k1 >= NKT) k1 -= NKT;
  stageA(0, start); stageB(0, start);
  stageA(1, k1);    stageB(1, k1);
  asm volatile("s_waitcnt vmcnt(8)" ::: "memory");
  __builtin_amdgcn_s_barrier();

  for (int it = 0; it < NKT; ++it) {
    const int pb = it & 1;
    const short* Ab = &Asm[pb][0];
    const short* Bb = &Bsm[pb][0];

    bf16x8 a0[8], b0[4], a1[8], b1[4];
    // ---- P0: read ks0 frags, MFMA (ks0, m-half 0) ----
#pragma unroll
    for (int i = 0; i < 8; ++i) a0[i] = *(const bf16x8*)(Ab + arow + i * 1024 + sl0);
#pragma unroll
    for (int j = 0; j < 4; ++j) b0[j] = *(const bf16x8*)(Bb + brow + j * 1024 + sl0);
    __builtin_amdgcn_s_barrier();
    __builtin_amdgcn_s_setprio(1);
#pragma unroll
    for (int i = 0; i < 4; ++i)
#pragma unroll
      for (int j = 0; j < 4; ++j)
        acc[i][j] = __builtin_amdgcn_mfma_f32_16x16x32_bf16(a0[i], b0[j], acc[i][j], 0, 0, 0);
    __builtin_amdgcn_s_setprio(0);

    // ---- P1: read ks1 frags, MFMA (ks0, m-half 1), then read-complete gate
    #pragma unroll
    for (int i = 0; i < 8; ++i) a1[i] = *(const bf16x8*)(Ab + arow + i * 1024 + sl1);
#pragma unroll
    for (int j = 0; j < 4; ++j) b1[j] = *(const bf16x8*)(Bb + brow + j * 1024 + sl1);
    __builtin_amdgcn_s_barrier();
    asm volatile("s_waitcnt lgkmcnt(0)" ::: "memory");  // ALL my buf[pb] reads done
    __builtin_amdgcn_s_setprio(1);
#pragma unroll
    for (int i = 4; i < 8; ++i)
#pragma unroll
      for (int j = 0; j < 4; ++j)
        acc[i][j] = __builtin_amdgcn_mfma_f32_16x16x32_bf16(a0[i], b0[j], acc[i][j], 0, 0, 0);
    __builtin_amdgcn_s_setprio(0);
    __builtin_amdgcn_s_barrier();  // gate: every wave finished reading buf[pb]

    // ---- P2/P3: stage tile it+2 into buf[pb]; MFMA ks1 from registers ----
    const int it2 = it + 2;
    int kit2 = start + it2; if (kit2 >= NKT) kit2 -= NKT;
    const bool stg = (it2 < NKT);
    if (stg) stageA(pb, kit2);
    __builtin_amdgcn_s_setprio(1);
#pragma unroll
    for (int i = 0; i < 4; ++i)
#pragma unroll
      for (int j = 0; j < 4; ++j)
        acc[i][j] = __builtin_amdgcn_mfma_f32_16x16x32_bf16(a1[i], b1[j], acc[i][j], 0, 0, 0);
    __builtin_amdgcn_s_setprio(0);
    if (stg) stageB(pb, kit2);
    __builtin_amdgcn_s_setprio(1);
#pragma unroll
    for (int i = 4; i < 8; ++i)
#pragma unroll
      for (int j = 0; j < 4; ++j)
        acc[i][j] = __builtin_amdgcn_mfma_f32_16x16x32_bf16(a1[i], b1[j], acc[i][j], 0, 0, 0);
    __builtin_amdgcn_s_setprio(0);
    // Confirm tile it+1 (oldest 8); keep tile it+2's 8 loads in flight.
    if (stg) asm volatile("s_waitcnt vmcnt(8)" ::: "memory");
    else     asm volatile("s_waitcnt vmcnt(0)" ::: "memory");
    __builtin_amdgcn_s_barrier();
  }

  // Epilogue: bias + relu + bf16 store.
#pragma unroll
  for (int j = 0; j < 4; ++j) {
    const int n = n0 + (wn << 6) + (j << 4) + l15;
    const float bv = (n < NR) ? bias[n] : 0.f;
#pragma unroll
    for (int i = 0; i < 8; ++i) {
      const int mr = m0 + (wm << 7) + (i << 4) + (quad << 2);
#pragma unroll
      for (int r = 0; r < 4; ++r) {
        float v = acc[i][j][r] + bv;
        v = v > 0.f ? v : 0.f;
        Hout[(size_t)(mr + r) * NP + n] = (short)f2bf(v);
      }
    }
  }
}

// ---------------------------------------------------------------------------
// Fallback GEMM1 (small-ws): fused fp32->bf16 convert, m97 BK=32, KP=832.
// ---------------------------------------------------------------------------
__global__ __launch_bounds__(256, 2)
void gemm1_fused_kernel(const float* __restrict__ X, const short* __restrict__ Wb,
                        const float* __restrict__ bias, short* __restrict__ H) {
  constexpr int K = 784, KP = 832, NP = 1024, NR = 1000;
  __shared__ short As[128 * 32];
  __shared__ short Bs[128 * 32];

  const int tid = threadIdx.x;
  const int lane = tid & 63;
  const int wave = tid >> 6;
  const int wm = wave >> 1, wn = wave & 1;
  const int l15 = lane & 15;
  const int quad = lane >> 4;
  const int m0 = blockIdx.y * 128;
  const int n0 = blockIdx.x * 128;

  const int ar = tid >> 1;
  const int aks = (tid & 1) * 16;
  const float* xrow = X + (size_t)(m0 + ar) * K;
  short* adst = As + ar * 32 + aks;

  const int br = wave * 16 + (lane >> 2);
  const int bks = (lane & 3) * 8;
  const short* brow0 = Wb + (size_t)(n0 + br) * KP + bks;
  short* bdst = Bs + (wave * 16) * 32;

  f32x4 acc[4][4];
#pragma unroll
  for (int i = 0; i < 4; ++i)
#pragma unroll
    for (int j2 = 0; j2 < 4; ++j2) acc[i][j2] = (f32x4){0.f, 0.f, 0.f, 0.f};

  for (int k0 = 0; k0 < KP; k0 += 32) {
    glds16(brow0 + k0, bdst);
    glds16(brow0 + k0 + (size_t)64 * KP, bdst + 64 * 32);
    short tmp[16];
#pragma unroll
    for (int c = 0; c < 4; ++c) {
      const int kk = k0 + aks + c * 4;
      float4 f;
      if (kk + 3 < K)
        f = *(const float4*)(xrow + kk);
      else
        f = make_float4(0.f, 0.f, 0.f, 0.f);
      tmp[c * 4 + 0] = (short)f2bf(f.x);
      tmp[c * 4 + 1] = (short)f2bf(f.y);
      tmp[c * 4 + 2] = (short)f2bf(f.z);
      tmp[c * 4 + 3] = (short)f2bf(f.w);
    }
    *(bf16x8*)(adst) = *(bf16x8*)(tmp);
    *(bf16x8*)(adst + 8) = *(bf16x8*)(tmp + 8);
    __syncthreads();

    const short* abase = As + (size_t)(wm * 64 + l15) * 32 + quad * 8;
    const short* bbase = Bs + (size_t)(wn * 64 + l15) * 32 + quad * 8;
    bf16x8 af[4], bfr[4];
#pragma unroll
    for (int i = 0; i < 4; ++i) af[i] = *(const bf16x8*)(abase + i * 16 * 32);
#pragma unroll
    for (int j2 = 0; j2 < 4; ++j2) bfr[j2] = *(const bf16x8*)(bbase + j2 * 16 * 32);
#pragma unroll
    for (int i = 0; i < 4; ++i)
#pragma unroll
      for (int j2 = 0; j2 < 4; ++j2)
        acc[i][j2] = __builtin_amdgcn_mfma_f32_16x16x32_bf16(af[i], bfr[j2], acc[i][j2], 0, 0, 0);
    __syncthreads();
  }

#pragma unroll
  for (int j2 = 0; j2 < 4; ++j2) {
    const int n = n0 + wn * 64 + j2 * 16 + l15;
    const float bv = (n < NR) ? bias[n] : 0.f;
#pragma unroll
    for (int i = 0; i < 4; ++i) {
      const int mr = m0 + wm * 64 + i * 16 + quad * 4;
#pragma unroll
      for (int r = 0; r < 4; ++r) {
        float v = acc[i][j2][r] + bv;
        v = v > 0.f ? v : 0.f;
        H[(size_t)(mr + r) * NP + n] = (short)f2bf(v);
      }
    }
  }
}

// ---------------------------------------------------------------------------
// GEMM3: h2 bf16 [65536,512] x W3b [16,512] -> out f32 [65536,10]
// ---------------------------------------------------------------------------
__global__ __launch_bounds__(256, 2)
void gemm3_kernel(const short* __restrict__ Hin, const short* __restrict__ Wb,
                  const float* __restrict__ bias, float* __restrict__ Out) {
  constexpr int KP = 512;
  __shared__ short As[64 * KP];

  const int tid = threadIdx.x;
  const int lane = tid & 63;
  const int wave = tid >> 6;
  const int l15 = lane & 15;
  const int quad = lane >> 4;
  const int m0 = blockIdx.x * 64;

  bf16x8 bw[16];
#pragma unroll
  for (int kk = 0; kk < 16; ++kk)
    bw[kk] = *(const bf16x8*)(Wb + l15 * KP + kk * 32 + quad * 8);

  const short* asrc = Hin + (size_t)(m0 + wave * 16) * KP + lane * 8;
  short* adst = As + (size_t)(wave * 16) * KP;
#pragma unroll
  for (int t = 0; t < 16; ++t)
    glds16(asrc + (size_t)t * KP, adst + (size_t)t * KP);

  __syncthreads();

  f32x4 acc = (f32x4){0.f, 0.f, 0.f, 0.f};
  const short* abase = As + (size_t)(wave * 16 + l15) * KP + quad * 8;
#pragma unroll
  for (int kk = 0; kk < 16; ++kk) {
    bf16x8 af = *(const bf16x8*)(abase + kk * 32);
    acc = __builtin_amdgcn_mfma_f32_16x16x32_bf16(af, bw[kk], acc, 0, 0, 0);
  }

  if (l15 < 10) {
    const float bv = bias[l15];
#pragma unroll
    for (int r = 0; r < 4; ++r) {
      const int mr = m0 + wave * 16 + quad * 4 + r;
      Out[(size_t)mr * 10 + l15] = acc[r] + bv;
    }
  }
}

// ---------------------------------------------------------------------------
extern "C" void kernel_launch(void* const* d_in, const int* in_sizes, int n_in,
                              void* d_out, int out_size, void* d_ws, size_t ws_size,
                              hipStream_t stream) {
  const float* x = (const float*)d_in[0];
  const float* W1 = (const float*)d_in[1];
  const float* b1 = (const float*)d_in[2];
  const float* W2 = (const float*)d_in[3];
  const float* b2 = (const float*)d_in[4];
  const float* W3 = (const float*)d_in[5];
  const float* b3 = (const float*)d_in[6];
  float* out = (float*)d_out;

  const size_t szW1 = (size_t)1024 * 832 * 2;
  const size_t szW2 = (size_t)512 * 1024 * 2;
  const size_t szW3 = (size_t)16 * 512 * 2;
  const size_t szH1 = (size_t)65536 * 1024 * 2;
  const size_t szXp = (size_t)65536 * 832 * 2;  // shares Z with h2
  const size_t need = szW1 + szW2 + szW3 + szH1 + szXp;  // ~246 MB

  uint8_t* p = (uint8_t*)d_ws;
  short* W1b = (short*)p; p += szW1;
  short* W2b = (short*)p; p += szW2;
  short* W3b = (short*)p; p += szW3;
  short* h1 = (short*)p; p += szH1;
  short* Z = (short*)p;  // Xp (convert+gemm1), then h2 (gemm2+gemm3)

  binarize_kernel<<<(1024 * 832 + 255) / 256, 256, 0, stream>>>(W1, 1000, 784, W1b, 1024, 832);
  binarize_kernel<<<(512 * 1024 + 255) / 256, 256, 0, stream>>>(W2, 500, 1000, W2b, 512, 1024);
  binarize_kernel<<<(16 * 512 + 255) / 256, 256, 0, stream>>>(W3, 10, 500, W3b, 16, 512);

  if (ws_size >= need) {
    short* Xp = Z;
    short* h2 = Z;
    convert_x_kernel<<<(65536 * 104 + 255) / 256, 256, 0, stream>>>(x, Xp);
    gemm256<832, 13, 1024, 1000, 4><<<1024, 512, 0, stream>>>(Xp, W1b, b1, h1);
    gemm256<1024, 16, 512, 500, 2><<<512, 512, 0, stream>>>(h1, W2b, b2, h2);
    gemm3_kernel<<<1024, 256, 0, stream>>>(h2, W3b, b3, out);
  } else {
    short* h2 = Z;
    gemm1_fused_kernel<<<dim3(8, 512), 256, 0, stream>>>(x, W1b, b1, h1);
    gemm256<1024, 16, 512, 500, 2><<<512, 512, 0, stream>>>(h1, W2b, b2, h2);
    gemm3_kernel<<<1024, 256, 0, stream>>>(h2, W3b, b3, out);
  }
}